// Round 10
// baseline (171.455 us; speedup 1.0000x reference)
//
#include <hip/hip_runtime.h>

// N = 8,388,608 rows, C = 3 classes (fp32 log-probs), int32 labels.
// out = -sum_i( w_i * pre[i, y_i] ) / N, w_i = (|argmax(pre_i) - y_i| == 2) ? weight : 1
//
// History (kernel-only; total dur_us carries ~121 us of harness poison fills):
//   R0 one-shot strided + atomic:          ~49 us
//   R1 one-shot coalesced + barrier:        63.5 us
//   R2 one-shot coalesced wave-private:     ~50 us
//   R3 persistent pipelined + atomic:       ~52 us
//   R4 persistent NT + atomic-free:         ~33 us main + ~2 reduce   (4.06 TB/s)
// R3->R4 delta ~18 us == the 1024-same-address-atomic tail (cross-XCD RMW
// serialization). NT was ~neutral: cached loads also ran ~33 us ex-tail.
//
// R5 (this): kill the LDS round-trip entirely. Each lane loads 3 CONSECUTIVE
// float4s (48B lane stride) -> owns rows 4l..4l+3 fully in registers; the 4x3
// "transpose" is static component swizzles. Labels collapse to ONE coalesced
// int4 load (VMEM instrs 7 -> 4 per chunk). The 3x line-touch inflation of
// 48B-stride loads was shown ~free (R0 vs R2). NT dropped (neutral; cached
// re-enables the ~67MB of L3 hits R1's FETCH_SIZE demonstrated). No LDS ->
// no lgkmcnt serialization, no LDS pipe, and occupancy can reach 32 waves/CU
// (grid 2048 fully resident). 3-deep register pipeline as in R4.

typedef float v4f __attribute__((ext_vector_type(4)));
typedef int   v4i __attribute__((ext_vector_type(4)));

#define N_ROWS   8388608
#define BLOCK    256
#define GRID     2048
#define WPB      (BLOCK / 64)            // 4 waves/block
#define NWAVES   (GRID * WPB)            // 8192
#define ROWS_PW  (N_ROWS / NWAVES)       // 1024 contiguous rows per wave
#define NITER    4                       // 4 chunks of 256 rows per wave

__device__ __forceinline__ float row3(float p0, float p1, float p2, int tt, float wgt) {
    const float picked = (tt == 0) ? p0 : ((tt == 1) ? p1 : p2);
    // first-occurrence argmax over 3 (matches jnp.argmax tie-break)
    int   prd = 0;
    float mx  = p0;
    if (p1 > mx) { mx = p1; prd = 1; }
    if (p2 > mx) { prd = 2; }
    const bool penal = (prd - tt == 2) || (tt - prd == 2);
    return (penal ? wgt : 1.0f) * picked;
}

__global__ __launch_bounds__(BLOCK) void nll_main(
        const float* __restrict__ pre,
        const int*   __restrict__ y_true,
        const float* __restrict__ wptr,
        float*       __restrict__ partial) {
    const float wgt  = wptr[0];
    const int   t    = threadIdx.x;
    const int   lane = t & 63;
    const int   wv   = t >> 6;
    const int   W    = (int)blockIdx.x * WPB + wv;   // global wave id [0, 8192)

    const v4f* __restrict__ pre4 = (const v4f*)pre;
    const v4i* __restrict__ y4   = (const v4i*)y_true;

    // Lane l, iter k owns rows W*1024 + k*256 + 4l .. +3:
    //   pre  float4 base = W*768 + k*192 + 3l   (48B lane stride, 3 consecutive f4)
    //   y    int4   base = W*256 + k*64  + l    (16B lane stride, coalesced)
    // Max pre4 idx = 8191*768 + 3*192 + 3*63 + 2 = 6,291,455 = count-1. Exact.
    const int fbW = W * 768 + 3 * lane;
    const int ybW = W * 256 + lane;

    // 3-deep pipeline registers: 36 (pre) + 12 (labels) VGPR
    v4f v[3][3];
    v4i y[3];

    // ---- prologue: chunks 0 and 1 in flight (8 loads) ----------------------
    #pragma unroll
    for (int p = 0; p < 2; ++p) {
        v[p][0] = pre4[fbW + p * 192 + 0];
        v[p][1] = pre4[fbW + p * 192 + 1];
        v[p][2] = pre4[fbW + p * 192 + 2];
        y[p]    = y4[ybW + p * 64];
    }

    float acc = 0.0f;
    #pragma unroll
    for (int k = 0; k < NITER; ++k) {        // fully unrolled: all indices static
        const int b  = k % 3;                // buffer being consumed
        const int nb = (k + 2) % 3;          // buffer being refilled

        // Prefetch chunk k+2 before consuming chunk k: 2 chunks always in
        // flight per wave; the compiler's partial vmcnt releases chunk k only.
        if (k + 2 < NITER) {
            v[nb][0] = pre4[fbW + (k + 2) * 192 + 0];
            v[nb][1] = pre4[fbW + (k + 2) * 192 + 1];
            v[nb][2] = pre4[fbW + (k + 2) * 192 + 2];
            y[nb]    = y4[ybW + (k + 2) * 64];
        }

        // Rows live entirely in registers: 12 floats = 4 rows x 3 classes.
        const v4f a  = v[b][0], c = v[b][1], d = v[b][2];
        const v4i yy = y[b];
        acc += row3(a.x, a.y, a.z, yy.x, wgt);
        acc += row3(a.w, c.x, c.y, yy.y, wgt);
        acc += row3(c.z, c.w, d.x, yy.z, wgt);
        acc += row3(d.y, d.z, d.w, yy.w, wgt);
    }

    // ---- block partial: wave shuffle + tiny LDS combine, NO atomics --------
    #pragma unroll
    for (int off = 32; off > 0; off >>= 1)
        acc += __shfl_down(acc, off, 64);

    __shared__ float red[WPB];
    if (lane == 0) red[wv] = acc;
    __syncthreads();                       // after ALL memory work: harmless

    if (t == 0)
        partial[blockIdx.x] = red[0] + red[1] + red[2] + red[3];
}

// Second launch on the same stream (graph-legal): reduce 2048 partials.
__global__ __launch_bounds__(512) void nll_reduce(
        const float* __restrict__ partial,
        float*       __restrict__ out) {
    const float4 p = ((const float4*)partial)[threadIdx.x];   // 512*4 = 2048
    float s = p.x + p.y + p.z + p.w;
    #pragma unroll
    for (int off = 32; off > 0; off >>= 1)
        s += __shfl_down(s, off, 64);

    __shared__ float r[8];
    if ((threadIdx.x & 63) == 0) r[threadIdx.x >> 6] = s;
    __syncthreads();
    if (threadIdx.x == 0) {
        float tot = 0.0f;
        #pragma unroll
        for (int i = 0; i < 8; ++i) tot += r[i];
        out[0] = tot * (-1.0f / (float)N_ROWS);
    }
}

extern "C" void kernel_launch(void* const* d_in, const int* in_sizes, int n_in,
                              void* d_out, int out_size, void* d_ws, size_t ws_size,
                              hipStream_t stream) {
    const float* pre  = (const float*)d_in[0];
    const int*   y    = (const int*)d_in[1];
    const float* wptr = (const float*)d_in[2];
    float* ws  = (float*)d_ws;       // 8 KiB of workspace for 2048 partials
    float* out = (float*)d_out;

    nll_main<<<GRID, BLOCK, 0, stream>>>(pre, y, wptr, ws);
    nll_reduce<<<1, 512, 0, stream>>>(ws, out);
}